// Round 19
// baseline (312.006 us; speedup 1.0000x reference)
//
#include <hip/hip_runtime.h>
#include <hip/hip_bf16.h>
#include <math.h>

// Problem constants
#define BN   8
#define SN   2048
#define HN   1024
#define NTOK 16384   // B*S
#define NHD  16
#define HDD  64
#define NSD  64

typedef __attribute__((ext_vector_type(8))) short short8;
typedef __attribute__((ext_vector_type(4))) float f32x4;

__device__ __forceinline__ float fsig(float x)  { return 1.f / (1.f + __expf(-x)); }
__device__ __forceinline__ float fsilu(float x) { return x / (1.f + __expf(-x)); }
__device__ __forceinline__ float ftanh(float x) {
    const float t = __expf(-2.f * fabsf(x));
    const float r = (1.f - t) / (1.f + t);
    return x >= 0.f ? r : -r;
}
__device__ __forceinline__ unsigned pack_cd(float cand, float dec) {
    __hip_bfloat16 cb_ = __float2bfloat16(cand);
    __hip_bfloat16 db_ = __float2bfloat16(dec);
    return (unsigned)*(unsigned short*)&cb_ | ((unsigned)*(unsigned short*)&db_ << 16);
}
__device__ __forceinline__ float bf2f(unsigned short u) {
    return __uint_as_float((unsigned)u << 16);
}
__device__ __forceinline__ void gload_lds16(const void* g, void* l) {
    __builtin_amdgcn_global_load_lds(
        (const __attribute__((address_space(1))) unsigned int*)g,
        (__attribute__((address_space(3))) unsigned int*)l, 16, 0, 0);
}

// ---------------------------------------------------------------------------
// x (16384x1024 f32) -> A (16384x1024 bf16), pre-swizzled in 4-octet groups:
// logical octet c of row r stored at (c&~3)|((c&3)^((r>>1)&3)).
// ---------------------------------------------------------------------------
__global__ __launch_bounds__(256)
void x_to_a_bf(const float* __restrict__ X, __hip_bfloat16* __restrict__ A)
{
    const int idx = blockIdx.x * 256 + threadIdx.x;   // 2M octets
    const int r = idx >> 7;
    const int c = idx & 127;                          // logical octet
    const float* src = &X[(size_t)r * 1024 + c * 8];
    alignas(16) __hip_bfloat16 b[8];
#pragma unroll
    for (int j = 0; j < 8; ++j) b[j] = __float2bfloat16(src[j]);
    const int cs = (c & ~3) | ((c & 3) ^ ((r >> 1) & 3));
    *(short8*)&A[(size_t)r * 1024 + cs * 8] = *(const short8*)b;
}

// ---------------------------------------------------------------------------
// W (1024 x N f32, (in,out)) -> BT (N x 1024 bf16), same 4-group pre-swizzle.
// ---------------------------------------------------------------------------
__global__ __launch_bounds__(256)
void w_to_bt_bf(const float* __restrict__ W, __hip_bfloat16* __restrict__ BT, int N)
{
    __shared__ float t[64][65];
    const int k0 = blockIdx.x * 64;
    const int n0 = blockIdx.y * 64;
    const int c  = threadIdx.x & 63, r4 = threadIdx.x >> 6;
#pragma unroll
    for (int rr = 0; rr < 64; rr += 4)
        t[rr + r4][c] = W[(size_t)(k0 + rr + r4) * N + n0 + c];
    __syncthreads();
#pragma unroll
    for (int oo = 0; oo < 2; ++oo) {
        const int o = r4 * 2 + oo;                 // octet within 64-k tile
        alignas(16) __hip_bfloat16 b[8];
#pragma unroll
        for (int j = 0; j < 8; ++j)
            b[j] = __float2bfloat16(t[o * 8 + j][c]);
        const int n = n0 + c;
        const int cglob = (k0 >> 3) + o;           // global octet index
        const int cs = (cglob & ~3) | ((cglob & 3) ^ ((n >> 1) & 3));
        *(short8*)&BT[(size_t)n * 1024 + cs * 8] = *(const short8*)b;
    }
}

// ---------------------------------------------------------------------------
// 5 backbone weight mats -> WT5 (backbone's own 8-group format, unchanged).
// ---------------------------------------------------------------------------
__global__ __launch_bounds__(256)
void w5_to_wt(const float* __restrict__ w0, const float* __restrict__ w1,
              const float* __restrict__ w2, const float* __restrict__ w3,
              const float* __restrict__ w4, __hip_bfloat16* __restrict__ WT5)
{
    const int idx = blockIdx.x * 256 + threadIdx.x;
    if (idx >= 2560) return;
    const int o = idx & 7, n = (idx >> 3) & 63, mat = idx >> 9;
    const float* W = mat == 0 ? w0 : mat == 1 ? w1 : mat == 2 ? w2 : mat == 3 ? w3 : w4;
    alignas(16) __hip_bfloat16 b[8];
#pragma unroll
    for (int j = 0; j < 8; ++j)
        b[j] = __float2bfloat16(W[(o * 8 + j) * 64 + n]);
    *(short8*)&WT5[(size_t)(mat * 64 + n) * 64 + ((o ^ (n & 7)) * 8)] = *(const short8*)b;
}

// ---------------------------------------------------------------------------
// Pure-bf16 MFMA GEMM, 128x256 tile, BK=32, 8 waves (2Mx4N), wave-tile 64x64.
// acc[4][4]=64 regs, launch_bounds(512,4) -> 2 blocks/CU (48 KB LDS), no
// spills (VGPR 60 measured).  (512,6) spills acc to scratch — do NOT raise.
// 4-group swizzle with (row>>1)&3 -> conflict-free ds_read_b128.
// MODE 0: f32 C to outf.  MODE 1: cols<1024 -> bf16 xb; else silu -> bf16 zb.
// ---------------------------------------------------------------------------
template<int NCT, int MODE>
__global__ __launch_bounds__(512, 4)
void mfma_gemm(const __hip_bfloat16* __restrict__ A,
               const __hip_bfloat16* __restrict__ BT,
               float* __restrict__ outf,
               __hip_bfloat16* __restrict__ xb, __hip_bfloat16* __restrict__ zb)
{
    __shared__ __hip_bfloat16 lds[2][12288];   // [buf][A 128x32 | B 256x32]
    const int tid  = threadIdx.x;
    const int lane = tid & 63, wave = tid >> 6;
    const int wr   = wave >> 2, wc = wave & 3;     // 2 x 4 wave grid
    const int l15  = lane & 15, l4 = lane >> 4;

    // XCD-aware bijective swizzle (gridDim.x % 8 == 0 at both call sites)
    const int nwg = gridDim.x;
    const int cpx = nwg >> 3;
    const int swz = (blockIdx.x & 7) * cpx + (blockIdx.x >> 3);
    const int mt = swz / NCT, nt = swz % NCT;
    const int row0 = mt * 128, col0 = nt * 256;

    const int s_c = tid & 3;
    const int s_r = tid >> 2;          // 0..127

    f32x4 acc[4][4];
#pragma unroll
    for (int m = 0; m < 4; ++m)
#pragma unroll
        for (int n = 0; n < 4; ++n) acc[m][n] = (f32x4)0.f;

#define STAGE(TT, BUF)                                                         \
    {                                                                          \
        const int kk_ = (TT) << 5;                                             \
        gload_lds16(&A[(size_t)(row0 + s_r) * 1024 + kk_ + s_c * 8],           \
                    &lds[BUF][s_r * 32 + s_c * 8]);                            \
        _Pragma("unroll")                                                      \
        for (int h_ = 0; h_ < 2; ++h_) {                                       \
            const int r_ = h_ * 128 + s_r;                                     \
            gload_lds16(&BT[(size_t)(col0 + r_) * 1024 + kk_ + s_c * 8],       \
                        &lds[BUF][4096 + r_ * 32 + s_c * 8]);                  \
        }                                                                      \
    }

    // ---- prologue: stage K-tile 0 into buf 0 ----
    STAGE(0, 0)
    __syncthreads();

    for (int t = 0; t < 32; ++t) {
        const int cur = t & 1, nxt = cur ^ 1;
        if (t < 31) STAGE(t + 1, nxt)

        const int ch = (l4 ^ ((l15 >> 1) & 3)) * 8;   // conflict-free swizzle
        short8 af[4], bf[4];
#pragma unroll
        for (int m = 0; m < 4; ++m)
            af[m] = *(const short8*)&lds[cur][(wr * 64 + m * 16 + l15) * 32 + ch];
#pragma unroll
        for (int n = 0; n < 4; ++n)
            bf[n] = *(const short8*)&lds[cur][4096 + (wc * 64 + n * 16 + l15) * 32 + ch];

        __builtin_amdgcn_s_setprio(1);
#pragma unroll
        for (int m = 0; m < 4; ++m)
#pragma unroll
            for (int n = 0; n < 4; ++n)
                acc[m][n] = __builtin_amdgcn_mfma_f32_16x16x32_bf16(af[m], bf[n], acc[m][n], 0, 0, 0);
        __builtin_amdgcn_s_setprio(0);

        __syncthreads();   // reads of cur done + prefetch into nxt landed
    }
#undef STAGE

    // epilogue: C/D layout col=lane&15, row=(lane>>4)*4+q
    const int orow = l4 * 4, ocol = l15;
#pragma unroll
    for (int m = 0; m < 4; ++m)
#pragma unroll
        for (int n = 0; n < 4; ++n) {
            const int c = col0 + wc * 64 + n * 16 + ocol;
#pragma unroll
            for (int q = 0; q < 4; ++q) {
                const int r = row0 + wr * 64 + m * 16 + orow + q;
                const float v = acc[m][n][q];
                if (MODE == 0) {
                    outf[(size_t)r * (NCT * 256) + c] = v;
                } else {
                    if (c < 1024) xb[(size_t)r * 1024 + c] = __float2bfloat16(v);
                    else          zb[(size_t)r * 1024 + (c - 1024)] = __float2bfloat16(fsilu(v));
                }
            }
        }
}

// ---------------------------------------------------------------------------
// FUSED conv + pure-bf16 backbone (unchanged from round 18 — proven).
// ---------------------------------------------------------------------------
__global__ __launch_bounds__(512, 4)
void backbone_mfma(const __hip_bfloat16* __restrict__ xpath,
                   const float* __restrict__ cw, const float* __restrict__ cb,
                   const __hip_bfloat16* __restrict__ WT5,
                   const float* __restrict__ bbb,
                   const float* __restrict__ f1b, const float* __restrict__ f2b,
                   const float* __restrict__ taub, const float* __restrict__ taub2,
                   const float* __restrict__ decb,
                   unsigned* __restrict__ cd)
{
    __shared__ __hip_bfloat16 Wl[5 * 64 * 64];   // 40 KB
    __shared__ __hip_bfloat16 Bb[128 * 64];      // 16 KB
    const int tid  = threadIdx.x;
    const int lane = tid & 63, wave = tid >> 6;
    const int l15  = lane & 15, l4 = lane >> 4;
    const int e7   = l15 & 7;

#pragma unroll
    for (int r = 0; r < 5; ++r) {
        const int blk = r * 8 + wave;
        gload_lds16(WT5 + blk * 512 + lane * 8, Wl + blk * 512);
    }

    // ---- fused depthwise conv (K=4) + bias + silu -> A-frags in-register ----
    const int bt = blockIdx.x * 8 + wave;     // this wave's token
    const int t  = bt & (SN - 1);
    short8 xa[2];
#pragma unroll
    for (int s = 0; s < 2; ++s) {
        const int cb0 = l15 * 64 + (s * 4 + l4) * 8;   // lane's channel base
        float acc[8];
#pragma unroll
        for (int j = 0; j < 8; ++j) acc[j] = cb[cb0 + j];
        float4 cwv[8];
#pragma unroll
        for (int j = 0; j < 8; ++j) cwv[j] = *(const float4*)&cw[(cb0 + j) * 4];
        const float* cwf = (const float*)cwv;
#pragma unroll
        for (int k = 0; k < 4; ++k) {
            if (t - 3 + k >= 0) {
                const short8 u = *(const short8*)&xpath[(size_t)(bt - 3 + k) * 1024 + cb0];
#pragma unroll
                for (int j = 0; j < 8; ++j)
                    acc[j] += cwf[j * 4 + k] * bf2f((unsigned short)u[j]);
            }
        }
        alignas(16) __hip_bfloat16 b[8];
#pragma unroll
        for (int j = 0; j < 8; ++j) b[j] = __float2bfloat16(fsilu(acc[j]));
        xa[s] = *(const short8*)b;
    }

    __syncthreads();   // Wl staged (vmcnt drained)

#pragma unroll
    for (int nt = 0; nt < 4; ++nt) {
        short8 wb[2];
#pragma unroll
        for (int s = 0; s < 2; ++s)
            wb[s] = *(const short8*)&Wl[(nt * 16 + l15) * 64 + (((s * 4 + l4) ^ e7) * 8)];
        f32x4 ac = (f32x4)0.f;
        ac = __builtin_amdgcn_mfma_f32_16x16x32_bf16(xa[0], wb[0], ac, 0, 0, 0);
        ac = __builtin_amdgcn_mfma_f32_16x16x32_bf16(xa[1], wb[1], ac, 0, 0, 0);
        const int col = nt * 16 + l15;
        const float bc = bbb[col];
#pragma unroll
        for (int q = 0; q < 4; ++q) {
            const int r15 = l4 * 4 + q;
            Bb[(wave * 16 + r15) * 64 + ((col >> 3) ^ (r15 & 7)) * 8 + (col & 7)] =
                __float2bfloat16(fsilu(ac[q] + bc));
        }
    }
    // wave-private slab: no barrier needed

    short8 ba[2];
#pragma unroll
    for (int s = 0; s < 2; ++s)
        ba[s] = *(const short8*)&Bb[(wave * 16 + l15) * 64 + (((s * 4 + l4) ^ e7) * 8)];

#pragma unroll
    for (int nt = 0; nt < 4; ++nt) {
        f32x4 a2[4];
#pragma unroll
        for (int m = 0; m < 4; ++m) a2[m] = (f32x4)0.f;

#pragma unroll
        for (int mat = 0; mat < 4; ++mat) {
            short8 w2[2];
#pragma unroll
            for (int s = 0; s < 2; ++s)
                w2[s] = *(const short8*)&Wl[((mat + 1) * 64 + nt * 16 + l15) * 64 + (((s * 4 + l4) ^ e7) * 8)];
            a2[mat] = __builtin_amdgcn_mfma_f32_16x16x32_bf16(ba[0], w2[0], a2[mat], 0, 0, 0);
            a2[mat] = __builtin_amdgcn_mfma_f32_16x16x32_bf16(ba[1], w2[1], a2[mat], 0, 0, 0);
        }

        const int col = nt * 16 + l15;
        const float b1 = f1b[col], b2 = f2b[col];
        const float b3 = taub[col] + taub2[col], b4 = decb[col];
        const size_t Rbase = (size_t)blockIdx.x * 128 + wave * 16;
#pragma unroll
        for (int q = 0; q < 4; ++q) {
            const size_t R = Rbase + l4 * 4 + q;
            const float f1v = ftanh(a2[0][q] + b1);
            const float f2v = ftanh(a2[1][q] + b2);
            const float tv  = fsig (a2[2][q] + b3);
            const float dv  = fsig (a2[3][q] + b4);
            cd[R * 64 + col] = pack_cd(f1v * (1.f - tv) + f2v * tv, dv);
        }
    }
}

// ---------------------------------------------------------------------------
// Chunked scan passes 1+2 (packed cd input, unchanged).
// ---------------------------------------------------------------------------
__global__ __launch_bounds__(256)
void scan_compose(const unsigned* __restrict__ cd,
                  float* __restrict__ Ach, float* __restrict__ Bch)
{
    const int idx = blockIdx.x * 256 + threadIdx.x;
    const int p  = idx & 1023;
    const int rest = idx >> 10;
    const int ch = rest & 63, b = rest >> 6;
    float A = 1.f, Bv = 0.f;
    const size_t base = ((size_t)(b * SN + ch * 32) << 10) + p;
    for (int t = 0; t < 32; ++t) {
        const unsigned u = cd[base + ((size_t)t << 10)];
        const float c = __uint_as_float(u << 16);
        const float d = __uint_as_float(u & 0xffff0000u);
        A  *= d;
        Bv  = d * Bv + (1.f - d) * c;
    }
    Ach[(ch << 13) + (b << 10) + p] = A;
    Bch[(ch << 13) + (b << 10) + p] = Bv;
}

__global__ __launch_bounds__(256)
void scan_chunks(const float* __restrict__ Ach, const float* __restrict__ Bch,
                 float* __restrict__ hstart)
{
    const int q = blockIdx.x * 256 + threadIdx.x;
    float h = 0.f;
    for (int ch = 0; ch < 64; ++ch) {
        hstart[(ch << 13) + q] = h;
        h = Ach[(ch << 13) + q] * h + Bch[(ch << 13) + q];
    }
}

// ---------------------------------------------------------------------------
// FUSED scan_apply + state_out + gate.  Block = (b, 32-token chunk); 512 thr,
// 72 KB LDS -> 2 blocks/CU (the condition round-6's 128KB version lacked).
// Phase 1: 2 chains/thread, h written as swizzled bf16 into Hl (identical
// layout/rounding to the old Hhl).  Phase 2: stateout MFMA (8 waves x 64
// rows) + silu(z) gate -> gA (4-group swizzle).  Bit-identical math.
// ---------------------------------------------------------------------------
__global__ __launch_bounds__(512, 4)
void scanout_fused(const unsigned* __restrict__ cd,
                   const float* __restrict__ hstart,
                   const float* __restrict__ sow, const float* __restrict__ sob,
                   const __hip_bfloat16* __restrict__ zs,
                   __hip_bfloat16* __restrict__ gA)
{
    __shared__ __hip_bfloat16 Wl[64 * 64];    // 8 KB
    __shared__ __hip_bfloat16 Hl[512 * 64];   // 64 KB
    const int tid  = threadIdx.x;
    const int lane = tid & 63, wave = tid >> 6;
    const int l15  = lane & 15, l4 = lane >> 4;
    const int e7   = l15 & 7;
    const int b  = blockIdx.x >> 6;
    const int chk = blockIdx.x & 63;

    // sow (64x64 f32) -> Wl pure bf16, octet o at o^(n&7); 512 thr = 1 octet each
    {
        const int n = tid & 63;
        const int o = tid >> 6;   // 0..7
        alignas(16) __hip_bfloat16 bw[8];
#pragma unroll
        for (int j = 0; j < 8; ++j)
            bw[j] = __float2bfloat16(sow[(o * 8 + j) * 64 + n]);
        *(short8*)&Wl[n * 64 + ((o ^ (n & 7)) * 8)] = *(const short8*)bw;
    }

    // ---- phase 1: scan 32 steps, 2 chains per thread -> Hl ----
    const float* hs0 = hstart + (chk << 13) + (b << 10);
    const int t0 = b * SN + chk * 32;
#pragma unroll
    for (int cp = 0; cp < 2; ++cp) {
        const int p = tid + cp * 512;
        const int nh = p >> 6, ns = p & 63;
        const int hpos = ((ns >> 3) ^ (nh & 7)) * 8 + (ns & 7);
        float h = hs0[p];
        const size_t base = ((size_t)t0 << 10) + p;
        for (int t = 0; t < 32; ++t) {
            const unsigned u = cd[base + ((size_t)t << 10)];
            const float c = __uint_as_float(u << 16);
            const float d = __uint_as_float(u & 0xffff0000u);
            h = d * h + (1.f - d) * c;
            Hl[(t * 16 + nh) * 64 + hpos] = __float2bfloat16(h);
        }
    }
    __syncthreads();

    // ---- phase 2: MFMA state_out; wave owns rows [wave*64, +64) ----
    short8 ha[4][2];
#pragma unroll
    for (int mt = 0; mt < 4; ++mt)
#pragma unroll
        for (int s = 0; s < 2; ++s)
            ha[mt][s] = *(const short8*)&Hl[(wave * 64 + mt * 16 + l15) * 64 + (((s * 4 + l4) ^ e7) * 8)];

#pragma unroll
    for (int nt = 0; nt < 4; ++nt) {
        short8 wb[2];
#pragma unroll
        for (int s = 0; s < 2; ++s)
            wb[s] = *(const short8*)&Wl[(nt * 16 + l15) * 64 + (((s * 4 + l4) ^ e7) * 8)];
        f32x4 ac[4];
#pragma unroll
        for (int mt = 0; mt < 4; ++mt) ac[mt] = (f32x4)0.f;
#pragma unroll
        for (int mt = 0; mt < 4; ++mt) {
            ac[mt] = __builtin_amdgcn_mfma_f32_16x16x32_bf16(ha[mt][0], wb[0], ac[mt], 0, 0, 0);
            ac[mt] = __builtin_amdgcn_mfma_f32_16x16x32_bf16(ha[mt][1], wb[1], ac[mt], 0, 0, 0);
        }
        const int col = nt * 16 + l15;
        const float bj = sob[col];
#pragma unroll
        for (int mt = 0; mt < 4; ++mt)
#pragma unroll
            for (int q = 0; q < 4; ++q) {
                const int rloc  = wave * 64 + mt * 16 + l4 * 4 + q;   // local row
                const int tokl  = rloc >> 4, nh = rloc & 15;
                const size_t token = (size_t)t0 + tokl;
                const float z = bf2f(*(const unsigned short*)&zs[token * 1024 + nh * 64 + col]);
                const float v = (ac[mt][q] + bj) * z;
                const int colg = nh * 64 + col;              // 0..1023
                const int cg = colg >> 3, jg = colg & 7;     // octet, elem
                const int cs = (cg & ~3) | ((cg & 3) ^ ((int)((token >> 1) & 3)));
                gA[token * 1024 + cs * 8 + jg] = __float2bfloat16(v);
            }
    }
}

// ---------------------------------------------------------------------------
extern "C" void kernel_launch(void* const* d_in, const int* in_sizes, int n_in,
                              void* d_out, int out_size, void* d_ws, size_t ws_size,
                              hipStream_t stream)
{
    const float* x     = (const float*)d_in[0];
    const float* ipw   = (const float*)d_in[1];
    const float* cw    = (const float*)d_in[2];
    const float* cb    = (const float*)d_in[3];
    const float* bbw   = (const float*)d_in[4];
    const float* bbb   = (const float*)d_in[5];
    const float* f1w   = (const float*)d_in[6];
    const float* f1b   = (const float*)d_in[7];
    const float* f2w   = (const float*)d_in[8];
    const float* f2b   = (const float*)d_in[9];
    const float* tauw  = (const float*)d_in[10];
    const float* taub  = (const float*)d_in[11];
    const float* taub2 = (const float*)d_in[12];
    const float* decw  = (const float*)d_in[13];
    const float* decb  = (const float*)d_in[14];
    const float* sow   = (const float*)d_in[15];
    const float* sob   = (const float*)d_in[16];
    const float* opw   = (const float*)d_in[17];

    float* out = (float*)d_out;
    char*  ws  = (char*)d_ws;
    const size_t MB = 1024 * 1024;

    // Workspace map (198 MiB), no aliasing hazards:
    //  @0Mi   (32Mi): Abf (dead after GEMM-in)
    //  @64Mi  (64Mi): xpath_bf (32Mi, dead after backbone) -> gA (32Mi)
    //  @128Mi (64Mi): BTin (2Mi, dead after GEMM-in) -> cd (packed uint 64Mi)
    //  @192Mi (6Mi) : WT5 (40KB, dead after backbone) -> Ach|Bch|hst;
    //                 BTout (2Mi) overwrites Ach after scan_chunks (hst @+4Mi safe)
    __hip_bfloat16* Abf   = (__hip_bfloat16*)(ws);
    __hip_bfloat16* xpath = (__hip_bfloat16*)(ws + 64 * MB);
    __hip_bfloat16* gA    = (__hip_bfloat16*)(ws + 64 * MB);
    __hip_bfloat16* BTin  = (__hip_bfloat16*)(ws + 128 * MB);
    unsigned*       cd    = (unsigned*)(ws + 128 * MB);
    __hip_bfloat16* WT5   = (__hip_bfloat16*)(ws + 192 * MB);
    float*          Ach   = (float*)(ws + 192 * MB);
    float*          Bch   = Ach + 524288;
    float*          hst   = Bch + 524288;
    __hip_bfloat16* BTout = (__hip_bfloat16*)(ws + 192 * MB);
    __hip_bfloat16* zsilu = (__hip_bfloat16*)out;   // d_out as scratch until final GEMM

    // 1) conversions
    x_to_a_bf<<<8192, 256, 0, stream>>>(x, Abf);
    w_to_bt_bf<<<dim3(16, 32), 256, 0, stream>>>(ipw, BTin, 2048);
    w5_to_wt<<<10, 256, 0, stream>>>(bbw, f1w, f2w, tauw, decw, WT5);
    // 2) in_proj GEMM (2 blocks/CU, conflict-free) -> bf16 x_path + bf16 silu(z)
    mfma_gemm<8, 1><<<1024, 512, 0, stream>>>(Abf, BTin, nullptr, xpath, zsilu);
    // 3) FUSED conv + backbone (reads xpath directly) -> packed cand|decay
    backbone_mfma<<<2048, 512, 0, stream>>>(xpath, cw, cb, WT5, bbb, f1b, f2b,
                                            taub, taub2, decb, cd);
    // 4) chunked scan levels 1+2
    scan_compose<<<2048, 256, 0, stream>>>(cd, Ach, Bch);
    scan_chunks<<<32, 256, 0, stream>>>(Ach, Bch, hst);
    // 5) out_proj weight conversion (Ach/Bch dead; hst untouched)
    w_to_bt_bf<<<dim3(16, 16), 256, 0, stream>>>(opw, BTout, 1024);
    // 6) FUSED scan_apply + state_out + gate -> gA (4-group swizzle)
    scanout_fused<<<512, 512, 0, stream>>>(cd, hst, sow, sob, zsilu, gA);
    // 7) out_proj GEMM -> f32 out
    mfma_gemm<4, 0><<<512, 512, 0, stream>>>(gA, BTout, out, nullptr, nullptr);
}

// Round 20
// 304.004 us; speedup vs baseline: 1.0263x; 1.0263x over previous
//
#include <hip/hip_runtime.h>
#include <hip/hip_bf16.h>
#include <math.h>

// Problem constants
#define BN   8
#define SN   2048
#define HN   1024
#define NTOK 16384   // B*S
#define NHD  16
#define HDD  64
#define NSD  64

typedef __attribute__((ext_vector_type(8))) short short8;
typedef __attribute__((ext_vector_type(4))) float f32x4;

__device__ __forceinline__ float fsig(float x)  { return 1.f / (1.f + __expf(-x)); }
__device__ __forceinline__ float fsilu(float x) { return x / (1.f + __expf(-x)); }
__device__ __forceinline__ float ftanh(float x) {
    const float t = __expf(-2.f * fabsf(x));
    const float r = (1.f - t) / (1.f + t);
    return x >= 0.f ? r : -r;
}
__device__ __forceinline__ unsigned pack_cd(float cand, float dec) {
    __hip_bfloat16 cb_ = __float2bfloat16(cand);
    __hip_bfloat16 db_ = __float2bfloat16(dec);
    return (unsigned)*(unsigned short*)&cb_ | ((unsigned)*(unsigned short*)&db_ << 16);
}
__device__ __forceinline__ float bf2f(unsigned short u) {
    return __uint_as_float((unsigned)u << 16);
}
__device__ __forceinline__ void gload_lds16(const void* g, void* l) {
    __builtin_amdgcn_global_load_lds(
        (const __attribute__((address_space(1))) unsigned int*)g,
        (__attribute__((address_space(3))) unsigned int*)l, 16, 0, 0);
}

// ---------------------------------------------------------------------------
// x (16384x1024 f32) -> A (16384x1024 bf16), pre-swizzled in 4-octet groups:
// logical octet c of row r stored at (c&~3)|((c&3)^((r>>1)&3)).
// ---------------------------------------------------------------------------
__global__ __launch_bounds__(256)
void x_to_a_bf(const float* __restrict__ X, __hip_bfloat16* __restrict__ A)
{
    const int idx = blockIdx.x * 256 + threadIdx.x;   // 2M octets
    const int r = idx >> 7;
    const int c = idx & 127;                          // logical octet
    const float* src = &X[(size_t)r * 1024 + c * 8];
    alignas(16) __hip_bfloat16 b[8];
#pragma unroll
    for (int j = 0; j < 8; ++j) b[j] = __float2bfloat16(src[j]);
    const int cs = (c & ~3) | ((c & 3) ^ ((r >> 1) & 3));
    *(short8*)&A[(size_t)r * 1024 + cs * 8] = *(const short8*)b;
}

// ---------------------------------------------------------------------------
// W (1024 x N f32, (in,out)) -> BT (N x 1024 bf16), same 4-group pre-swizzle.
// ---------------------------------------------------------------------------
__global__ __launch_bounds__(256)
void w_to_bt_bf(const float* __restrict__ W, __hip_bfloat16* __restrict__ BT, int N)
{
    __shared__ float t[64][65];
    const int k0 = blockIdx.x * 64;
    const int n0 = blockIdx.y * 64;
    const int c  = threadIdx.x & 63, r4 = threadIdx.x >> 6;
#pragma unroll
    for (int rr = 0; rr < 64; rr += 4)
        t[rr + r4][c] = W[(size_t)(k0 + rr + r4) * N + n0 + c];
    __syncthreads();
#pragma unroll
    for (int oo = 0; oo < 2; ++oo) {
        const int o = r4 * 2 + oo;                 // octet within 64-k tile
        alignas(16) __hip_bfloat16 b[8];
#pragma unroll
        for (int j = 0; j < 8; ++j)
            b[j] = __float2bfloat16(t[o * 8 + j][c]);
        const int n = n0 + c;
        const int cglob = (k0 >> 3) + o;           // global octet index
        const int cs = (cglob & ~3) | ((cglob & 3) ^ ((n >> 1) & 3));
        *(short8*)&BT[(size_t)n * 1024 + cs * 8] = *(const short8*)b;
    }
}

// ---------------------------------------------------------------------------
// 5 backbone weight mats -> WT5 (backbone's own 8-group format, unchanged).
// ---------------------------------------------------------------------------
__global__ __launch_bounds__(256)
void w5_to_wt(const float* __restrict__ w0, const float* __restrict__ w1,
              const float* __restrict__ w2, const float* __restrict__ w3,
              const float* __restrict__ w4, __hip_bfloat16* __restrict__ WT5)
{
    const int idx = blockIdx.x * 256 + threadIdx.x;
    if (idx >= 2560) return;
    const int o = idx & 7, n = (idx >> 3) & 63, mat = idx >> 9;
    const float* W = mat == 0 ? w0 : mat == 1 ? w1 : mat == 2 ? w2 : mat == 3 ? w3 : w4;
    alignas(16) __hip_bfloat16 b[8];
#pragma unroll
    for (int j = 0; j < 8; ++j)
        b[j] = __float2bfloat16(W[(o * 8 + j) * 64 + n]);
    *(short8*)&WT5[(size_t)(mat * 64 + n) * 64 + ((o ^ (n & 7)) * 8)] = *(const short8*)b;
}

// ---------------------------------------------------------------------------
// Pure-bf16 MFMA GEMM, 128x256 tile, BK=32, 8 waves (2Mx4N), wave-tile 64x64.
// acc[4][4]=64 regs, launch_bounds(512,4) -> 2 blocks/CU (48 KB LDS), no
// spills (VGPR 60 measured).  (512,6) spills acc to scratch — do NOT raise.
// 4-group swizzle with (row>>1)&3 -> conflict-free ds_read_b128.
// MODE 0: f32 C to outf.  MODE 1: cols<1024 -> bf16 xb; else silu -> bf16 zb.
// ---------------------------------------------------------------------------
template<int NCT, int MODE>
__global__ __launch_bounds__(512, 4)
void mfma_gemm(const __hip_bfloat16* __restrict__ A,
               const __hip_bfloat16* __restrict__ BT,
               float* __restrict__ outf,
               __hip_bfloat16* __restrict__ xb, __hip_bfloat16* __restrict__ zb)
{
    __shared__ __hip_bfloat16 lds[2][12288];   // [buf][A 128x32 | B 256x32]
    const int tid  = threadIdx.x;
    const int lane = tid & 63, wave = tid >> 6;
    const int wr   = wave >> 2, wc = wave & 3;     // 2 x 4 wave grid
    const int l15  = lane & 15, l4 = lane >> 4;

    // XCD-aware bijective swizzle (gridDim.x % 8 == 0 at both call sites)
    const int nwg = gridDim.x;
    const int cpx = nwg >> 3;
    const int swz = (blockIdx.x & 7) * cpx + (blockIdx.x >> 3);
    const int mt = swz / NCT, nt = swz % NCT;
    const int row0 = mt * 128, col0 = nt * 256;

    const int s_c = tid & 3;
    const int s_r = tid >> 2;          // 0..127

    f32x4 acc[4][4];
#pragma unroll
    for (int m = 0; m < 4; ++m)
#pragma unroll
        for (int n = 0; n < 4; ++n) acc[m][n] = (f32x4)0.f;

#define STAGE(TT, BUF)                                                         \
    {                                                                          \
        const int kk_ = (TT) << 5;                                             \
        gload_lds16(&A[(size_t)(row0 + s_r) * 1024 + kk_ + s_c * 8],           \
                    &lds[BUF][s_r * 32 + s_c * 8]);                            \
        _Pragma("unroll")                                                      \
        for (int h_ = 0; h_ < 2; ++h_) {                                       \
            const int r_ = h_ * 128 + s_r;                                     \
            gload_lds16(&BT[(size_t)(col0 + r_) * 1024 + kk_ + s_c * 8],       \
                        &lds[BUF][4096 + r_ * 32 + s_c * 8]);                  \
        }                                                                      \
    }

    // ---- prologue: stage K-tile 0 into buf 0 ----
    STAGE(0, 0)
    __syncthreads();

    for (int t = 0; t < 32; ++t) {
        const int cur = t & 1, nxt = cur ^ 1;
        if (t < 31) STAGE(t + 1, nxt)

        const int ch = (l4 ^ ((l15 >> 1) & 3)) * 8;   // conflict-free swizzle
        short8 af[4], bf[4];
#pragma unroll
        for (int m = 0; m < 4; ++m)
            af[m] = *(const short8*)&lds[cur][(wr * 64 + m * 16 + l15) * 32 + ch];
#pragma unroll
        for (int n = 0; n < 4; ++n)
            bf[n] = *(const short8*)&lds[cur][4096 + (wc * 64 + n * 16 + l15) * 32 + ch];

        __builtin_amdgcn_s_setprio(1);
#pragma unroll
        for (int m = 0; m < 4; ++m)
#pragma unroll
            for (int n = 0; n < 4; ++n)
                acc[m][n] = __builtin_amdgcn_mfma_f32_16x16x32_bf16(af[m], bf[n], acc[m][n], 0, 0, 0);
        __builtin_amdgcn_s_setprio(0);

        __syncthreads();   // reads of cur done + prefetch into nxt landed
    }
#undef STAGE

    // epilogue: C/D layout col=lane&15, row=(lane>>4)*4+q
    const int orow = l4 * 4, ocol = l15;
#pragma unroll
    for (int m = 0; m < 4; ++m)
#pragma unroll
        for (int n = 0; n < 4; ++n) {
            const int c = col0 + wc * 64 + n * 16 + ocol;
#pragma unroll
            for (int q = 0; q < 4; ++q) {
                const int r = row0 + wr * 64 + m * 16 + orow + q;
                const float v = acc[m][n][q];
                if (MODE == 0) {
                    outf[(size_t)r * (NCT * 256) + c] = v;
                } else {
                    if (c < 1024) xb[(size_t)r * 1024 + c] = __float2bfloat16(v);
                    else          zb[(size_t)r * 1024 + (c - 1024)] = __float2bfloat16(fsilu(v));
                }
            }
        }
}

// ---------------------------------------------------------------------------
// FUSED conv + pure-bf16 backbone, 512 threads (8 waves), 56 KB LDS, 2 blk/CU.
// Wave = 1 token.  The MFMA A-frag is computed IN-REGISTER: lane (l15,l4),
// slice s owns channels l15*64 + (s*4+l4)*8 .. +8 — exactly the frag layout —
// so the K=4 depthwise conv runs per-lane on bf16 xpath (4 guarded short8
// loads/slice), silu'd and packed directly.  Bit-identical to the old
// conv_silu_bf -> Xbf -> backbone path; saves 64 MB traffic + one launch.
// ---------------------------------------------------------------------------
__global__ __launch_bounds__(512, 4)
void backbone_mfma(const __hip_bfloat16* __restrict__ xpath,
                   const float* __restrict__ cw, const float* __restrict__ cb,
                   const __hip_bfloat16* __restrict__ WT5,
                   const float* __restrict__ bbb,
                   const float* __restrict__ f1b, const float* __restrict__ f2b,
                   const float* __restrict__ taub, const float* __restrict__ taub2,
                   const float* __restrict__ decb,
                   unsigned* __restrict__ cd)
{
    __shared__ __hip_bfloat16 Wl[5 * 64 * 64];   // 40 KB
    __shared__ __hip_bfloat16 Bb[128 * 64];      // 16 KB
    const int tid  = threadIdx.x;
    const int lane = tid & 63, wave = tid >> 6;
    const int l15  = lane & 15, l4 = lane >> 4;
    const int e7   = l15 & 7;

#pragma unroll
    for (int r = 0; r < 5; ++r) {
        const int blk = r * 8 + wave;
        gload_lds16(WT5 + blk * 512 + lane * 8, Wl + blk * 512);
    }

    // ---- fused depthwise conv (K=4) + bias + silu -> A-frags in-register ----
    const int bt = blockIdx.x * 8 + wave;     // this wave's token
    const int t  = bt & (SN - 1);
    short8 xa[2];
#pragma unroll
    for (int s = 0; s < 2; ++s) {
        const int cb0 = l15 * 64 + (s * 4 + l4) * 8;   // lane's channel base
        float acc[8];
#pragma unroll
        for (int j = 0; j < 8; ++j) acc[j] = cb[cb0 + j];
        float4 cwv[8];
#pragma unroll
        for (int j = 0; j < 8; ++j) cwv[j] = *(const float4*)&cw[(cb0 + j) * 4];
        const float* cwf = (const float*)cwv;
#pragma unroll
        for (int k = 0; k < 4; ++k) {
            if (t - 3 + k >= 0) {
                const short8 u = *(const short8*)&xpath[(size_t)(bt - 3 + k) * 1024 + cb0];
#pragma unroll
                for (int j = 0; j < 8; ++j)
                    acc[j] += cwf[j * 4 + k] * bf2f((unsigned short)u[j]);
            }
        }
        alignas(16) __hip_bfloat16 b[8];
#pragma unroll
        for (int j = 0; j < 8; ++j) b[j] = __float2bfloat16(fsilu(acc[j]));
        xa[s] = *(const short8*)b;
    }

    __syncthreads();   // Wl staged (vmcnt drained)

#pragma unroll
    for (int nt = 0; nt < 4; ++nt) {
        short8 wb[2];
#pragma unroll
        for (int s = 0; s < 2; ++s)
            wb[s] = *(const short8*)&Wl[(nt * 16 + l15) * 64 + (((s * 4 + l4) ^ e7) * 8)];
        f32x4 ac = (f32x4)0.f;
        ac = __builtin_amdgcn_mfma_f32_16x16x32_bf16(xa[0], wb[0], ac, 0, 0, 0);
        ac = __builtin_amdgcn_mfma_f32_16x16x32_bf16(xa[1], wb[1], ac, 0, 0, 0);
        const int col = nt * 16 + l15;
        const float bc = bbb[col];
#pragma unroll
        for (int q = 0; q < 4; ++q) {
            const int r15 = l4 * 4 + q;
            Bb[(wave * 16 + r15) * 64 + ((col >> 3) ^ (r15 & 7)) * 8 + (col & 7)] =
                __float2bfloat16(fsilu(ac[q] + bc));
        }
    }
    // wave-private slab: no barrier needed

    short8 ba[2];
#pragma unroll
    for (int s = 0; s < 2; ++s)
        ba[s] = *(const short8*)&Bb[(wave * 16 + l15) * 64 + (((s * 4 + l4) ^ e7) * 8)];

#pragma unroll
    for (int nt = 0; nt < 4; ++nt) {
        f32x4 a2[4];
#pragma unroll
        for (int m = 0; m < 4; ++m) a2[m] = (f32x4)0.f;

#pragma unroll
        for (int mat = 0; mat < 4; ++mat) {
            short8 w2[2];
#pragma unroll
            for (int s = 0; s < 2; ++s)
                w2[s] = *(const short8*)&Wl[((mat + 1) * 64 + nt * 16 + l15) * 64 + (((s * 4 + l4) ^ e7) * 8)];
            a2[mat] = __builtin_amdgcn_mfma_f32_16x16x32_bf16(ba[0], w2[0], a2[mat], 0, 0, 0);
            a2[mat] = __builtin_amdgcn_mfma_f32_16x16x32_bf16(ba[1], w2[1], a2[mat], 0, 0, 0);
        }

        const int col = nt * 16 + l15;
        const float b1 = f1b[col], b2 = f2b[col];
        const float b3 = taub[col] + taub2[col], b4 = decb[col];
        const size_t Rbase = (size_t)blockIdx.x * 128 + wave * 16;
#pragma unroll
        for (int q = 0; q < 4; ++q) {
            const size_t R = Rbase + l4 * 4 + q;
            const float f1v = ftanh(a2[0][q] + b1);
            const float f2v = ftanh(a2[1][q] + b2);
            const float tv  = fsig (a2[2][q] + b3);
            const float dv  = fsig (a2[3][q] + b4);
            cd[R * 64 + col] = pack_cd(f1v * (1.f - tv) + f2v * tv, dv);
        }
    }
}

// ---------------------------------------------------------------------------
// Chunked scan passes 1+2 (packed cd input, unchanged).
// ---------------------------------------------------------------------------
__global__ __launch_bounds__(256)
void scan_compose(const unsigned* __restrict__ cd,
                  float* __restrict__ Ach, float* __restrict__ Bch)
{
    const int idx = blockIdx.x * 256 + threadIdx.x;
    const int p  = idx & 1023;
    const int rest = idx >> 10;
    const int ch = rest & 63, b = rest >> 6;
    float A = 1.f, Bv = 0.f;
    const size_t base = ((size_t)(b * SN + ch * 32) << 10) + p;
    for (int t = 0; t < 32; ++t) {
        const unsigned u = cd[base + ((size_t)t << 10)];
        const float c = __uint_as_float(u << 16);
        const float d = __uint_as_float(u & 0xffff0000u);
        A  *= d;
        Bv  = d * Bv + (1.f - d) * c;
    }
    Ach[(ch << 13) + (b << 10) + p] = A;
    Bch[(ch << 13) + (b << 10) + p] = Bv;
}

__global__ __launch_bounds__(256)
void scan_chunks(const float* __restrict__ Ach, const float* __restrict__ Bch,
                 float* __restrict__ hstart)
{
    const int q = blockIdx.x * 256 + threadIdx.x;
    float h = 0.f;
    for (int ch = 0; ch < 64; ++ch) {
        hstart[(ch << 13) + q] = h;
        h = Ach[(ch << 13) + q] * h + Bch[(ch << 13) + q];
    }
}

// ---------------------------------------------------------------------------
// scan_apply: final h per timestep as pure bf16 swizzled rows (unchanged).
// ---------------------------------------------------------------------------
__global__ __launch_bounds__(256)
void scan_apply(const unsigned* __restrict__ cd,
                const float* __restrict__ hstart, __hip_bfloat16* __restrict__ Hhl)
{
    const int idx = blockIdx.x * 256 + threadIdx.x;
    const int p  = idx & 1023;
    const int rest = idx >> 10;
    const int ch = rest & 63, b = rest >> 6;
    const int nh = p >> 6, ns = p & 63;
    const int hpos = ((ns >> 3) ^ (nh & 7)) * 8 + (ns & 7);
    float h = hstart[(ch << 13) + (b << 10) + p];
    const int t0 = b * SN + ch * 32;
    const size_t base = ((size_t)t0 << 10) + p;
    for (int t = 0; t < 32; ++t) {
        const unsigned u = cd[base + ((size_t)t << 10)];
        const float c = __uint_as_float(u << 16);
        const float d = __uint_as_float(u & 0xffff0000u);
        h = d * h + (1.f - d) * c;
        Hhl[((size_t)(t0 + t) * 16 + nh) * 64 + hpos] = __float2bfloat16(h);
    }
}

// ---------------------------------------------------------------------------
// Pure-bf16 MFMA state_out: out = H @ sow + sob, gated by silu(z) (bf16);
// emits bf16 gA rows in 4-group swizzle ((token>>1)&3) for out_proj.
// ---------------------------------------------------------------------------
__global__ __launch_bounds__(256, 4)
void stateout_mfma(const __hip_bfloat16* __restrict__ Hhl,
                   const float* __restrict__ sow, const float* __restrict__ sob,
                   const __hip_bfloat16* __restrict__ zs, __hip_bfloat16* __restrict__ gA)
{
    __shared__ __hip_bfloat16 Wl[64 * 64];    // 8 KB
    __shared__ __hip_bfloat16 Hl[128 * 64];   // 16 KB
    const int tid  = threadIdx.x;
    const int lane = tid & 63, wave = tid >> 6;
    const int l15  = lane & 15, l4 = lane >> 4;
    const int e7   = l15 & 7;

    {
        const int n = tid & 63;
        const int o0 = tid >> 6;   // 0..3
#pragma unroll
        for (int oo = 0; oo < 2; ++oo) {
            const int o = o0 + oo * 4;
            alignas(16) __hip_bfloat16 b[8];
#pragma unroll
            for (int j = 0; j < 8; ++j)
                b[j] = __float2bfloat16(sow[(o * 8 + j) * 64 + n]);
            *(short8*)&Wl[n * 64 + ((o ^ (n & 7)) * 8)] = *(const short8*)b;
        }
    }
    const __hip_bfloat16* hsrc = Hhl + (size_t)blockIdx.x * 8192;
#pragma unroll
    for (int r = 0; r < 4; ++r) {
        const int blk = r * 4 + wave;
        gload_lds16(hsrc + blk * 512 + lane * 8, Hl + blk * 512);
    }
    __syncthreads();

    short8 ha[2][2];
#pragma unroll
    for (int mt2 = 0; mt2 < 2; ++mt2)
#pragma unroll
        for (int s = 0; s < 2; ++s)
            ha[mt2][s] = *(const short8*)&Hl[(wave * 32 + mt2 * 16 + l15) * 64 + (((s * 4 + l4) ^ e7) * 8)];

#pragma unroll
    for (int nt = 0; nt < 4; ++nt) {
        short8 wb[2];
#pragma unroll
        for (int s = 0; s < 2; ++s)
            wb[s] = *(const short8*)&Wl[(nt * 16 + l15) * 64 + (((s * 4 + l4) ^ e7) * 8)];
        f32x4 ac[2] = {(f32x4)0.f, (f32x4)0.f};
#pragma unroll
        for (int mt2 = 0; mt2 < 2; ++mt2) {
            ac[mt2] = __builtin_amdgcn_mfma_f32_16x16x32_bf16(ha[mt2][0], wb[0], ac[mt2], 0, 0, 0);
            ac[mt2] = __builtin_amdgcn_mfma_f32_16x16x32_bf16(ha[mt2][1], wb[1], ac[mt2], 0, 0, 0);
        }
        const int col = nt * 16 + l15;
        const float bj = sob[col];
#pragma unroll
        for (int mt2 = 0; mt2 < 2; ++mt2)
#pragma unroll
            for (int q = 0; q < 4; ++q) {
                const size_t th = (size_t)blockIdx.x * 128 + wave * 32 + mt2 * 16 + l4 * 4 + q;
                const float z = bf2f(*(const unsigned short*)&zs[th * 64 + col]);
                const float v = (ac[mt2][q] + bj) * z;
                const size_t token = th >> 4;
                const int colg = (int)(th & 15) * 64 + col;   // 0..1023
                const int cg = colg >> 3, jg = colg & 7;      // octet, elem
                const int cs = (cg & ~3) | ((cg & 3) ^ ((int)((token >> 1) & 3)));
                gA[token * 1024 + cs * 8 + jg] = __float2bfloat16(v);
            }
    }
}

// ---------------------------------------------------------------------------
extern "C" void kernel_launch(void* const* d_in, const int* in_sizes, int n_in,
                              void* d_out, int out_size, void* d_ws, size_t ws_size,
                              hipStream_t stream)
{
    const float* x     = (const float*)d_in[0];
    const float* ipw   = (const float*)d_in[1];
    const float* cw    = (const float*)d_in[2];
    const float* cb    = (const float*)d_in[3];
    const float* bbw   = (const float*)d_in[4];
    const float* bbb   = (const float*)d_in[5];
    const float* f1w   = (const float*)d_in[6];
    const float* f1b   = (const float*)d_in[7];
    const float* f2w   = (const float*)d_in[8];
    const float* f2b   = (const float*)d_in[9];
    const float* tauw  = (const float*)d_in[10];
    const float* taub  = (const float*)d_in[11];
    const float* taub2 = (const float*)d_in[12];
    const float* decw  = (const float*)d_in[13];
    const float* decb  = (const float*)d_in[14];
    const float* sow   = (const float*)d_in[15];
    const float* sob   = (const float*)d_in[16];
    const float* opw   = (const float*)d_in[17];

    float* out = (float*)d_out;
    char*  ws  = (char*)d_ws;
    const size_t MB = 1024 * 1024;

    // Workspace map (198 MiB), no aliasing hazards:
    //  @0Mi   (32Mi): Abf (dead after GEMM-in)
    //  @32Mi  (32Mi): Hhl (pure bf16)
    //  @64Mi  (64Mi): xpath_bf (32Mi, dead after backbone) -> gA (32Mi)
    //  @128Mi (64Mi): BTin (2Mi, dead after GEMM-in) -> cd (packed uint 64Mi)
    //  @192Mi (6Mi) : WT5 (40KB, dead after backbone) -> Ach|Bch|hst;
    //                 BTout (2Mi) overwrites Ach after scan_chunks (hst @+4Mi safe)
    __hip_bfloat16* Abf   = (__hip_bfloat16*)(ws);
    __hip_bfloat16* Hhl   = (__hip_bfloat16*)(ws + 32 * MB);
    __hip_bfloat16* xpath = (__hip_bfloat16*)(ws + 64 * MB);
    __hip_bfloat16* gA    = (__hip_bfloat16*)(ws + 64 * MB);
    __hip_bfloat16* BTin  = (__hip_bfloat16*)(ws + 128 * MB);
    unsigned*       cd    = (unsigned*)(ws + 128 * MB);
    __hip_bfloat16* WT5   = (__hip_bfloat16*)(ws + 192 * MB);
    float*          Ach   = (float*)(ws + 192 * MB);
    float*          Bch   = Ach + 524288;
    float*          hst   = Bch + 524288;
    __hip_bfloat16* BTout = (__hip_bfloat16*)(ws + 192 * MB);
    __hip_bfloat16* zsilu = (__hip_bfloat16*)out;   // d_out as scratch until final GEMM

    // 1) conversions
    x_to_a_bf<<<8192, 256, 0, stream>>>(x, Abf);
    w_to_bt_bf<<<dim3(16, 32), 256, 0, stream>>>(ipw, BTin, 2048);
    w5_to_wt<<<10, 256, 0, stream>>>(bbw, f1w, f2w, tauw, decw, WT5);
    // 2) in_proj GEMM (2 blocks/CU, conflict-free) -> bf16 x_path + bf16 silu(z)
    mfma_gemm<8, 1><<<1024, 512, 0, stream>>>(Abf, BTin, nullptr, xpath, zsilu);
    // 3) FUSED conv + backbone (reads xpath directly) -> packed cand|decay
    backbone_mfma<<<2048, 512, 0, stream>>>(xpath, cw, cb, WT5, bbb, f1b, f2b,
                                            taub, taub2, decb, cd);
    // 4) chunked scan -> Hhl (pure bf16)
    scan_compose<<<2048, 256, 0, stream>>>(cd, Ach, Bch);
    scan_chunks<<<32, 256, 0, stream>>>(Ach, Bch, hst);
    scan_apply<<<2048, 256, 0, stream>>>(cd, hst, Hhl);
    // 5) out_proj weight conversion (Ach/Bch dead; hst untouched)
    w_to_bt_bf<<<dim3(16, 16), 256, 0, stream>>>(opw, BTout, 1024);
    // 6) state_out + gate (bf16 z) -> gA (4-group swizzle)
    stateout_mfma<<<2048, 256, 0, stream>>>(Hhl, sow, sob, zsilu, gA);
    // 7) out_proj GEMM -> f32 out
    mfma_gemm<4, 0><<<512, 512, 0, stream>>>(gA, BTout, out, nullptr, nullptr);
}